// Round 9
// baseline (898.705 us; speedup 1.0000x reference)
//
#include <hip/hip_runtime.h>

#define T_STEPS 500
#define BATCH   2048
#define NIN     12
#define NL1     38
#define NL2     7

// fp32 I/O, FLOAT64 internal math (inputs promoted f32->f64 exactly; all ops
// f64; outputs cast f64->f32 on store). Numerics notes:
//   - cur1 = x . W1[row]: f64 FMAs, 2 interleaved partial chains + 1 add.
//   - cur2 = sum of selected W2 row entries (spikes in {0,1}): f64 FMAs with
//     scalar-selected multiplier in {0.0,1.0}, 4 partial chains + 3 adds.
//     Reassociation perturbation ~1e-15/step; harness passes at absmax
//     3.1e-2 (measured r6/r8) — 13 orders of magnitude of headroom.
//   - V*spk1 as (sp ? vj : vj*0.0); mem - spk*thr as (sp ? mem-thr : mem) —
//     both exact vs the f64 ops they replace.
//
// Schedule:
//   - REGISTER PINNING (new, round 9): rounds 6+8 PMC both show
//     VGPR_Count=64 — too small for w2r[38] (76 VGPRs) + w1r[12] (24), so
//     the allocator REMATERIALIZES the weight loads inside the time loop
//     (~50 L1/L2 loads re-issued per timestep; invisible in FETCH_SIZE).
//     __launch_bounds__(256,2) alone did not change the allocation (r8).
//     Empty `asm volatile("" : "+v"(w))` after the one-time loads makes the
//     values asm-defined — un-rematerializable — forcing true residency.
//     Budget: ~175 VGPR < 256 allowed at 2 waves/SIMD; grid provides only
//     2 waves/SIMD (2048 waves / 1024 SIMDs), so occupancy is unchanged.
//   - layer 2 skewed one step: iteration t computes L1(t) and L2(t-1);
//     epilogue finishes L2(T-1).
//   - UNIFIED membrane update folds L1/L2 updates + stores into one path.
//   - x prefetched 2 steps ahead as 3x float4.
//   - b pinned wave-uniform via readfirstlane (scalar x-address chain).
//   - bounds checks hoisted (audited: safeAll TRUE at exact output size).
//   - NONTEMPORAL output stores (write stream never re-read in-kernel).
// One wave per batch element: lanes 0..37 = layer-1 neurons, 38..44 = layer-2.
__global__ __launch_bounds__(256, 2) void snn_kernel(
    const float* __restrict__ x,  const float* __restrict__ W1,
    const float* __restrict__ V,  const float* __restrict__ W2,
    const float* __restrict__ b1p, const float* __restrict__ b2p,
    const float* __restrict__ thrp, float* __restrict__ out, int out_n)
{
#pragma clang fp contract(off)
    const int tid  = threadIdx.x;
    const int lane = tid & 63;
    const int wave = tid >> 6;
    // b is wave-uniform by construction; readfirstlane makes that visible to
    // the compiler (SGPR), scalarizing the x-address chain below.
    const int b    = __builtin_amdgcn_readfirstlane(blockIdx.x * 4 + wave);

    const double beta1 = (double)b1p[0];
    const double beta2 = (double)b2p[0];
    const double thr   = (double)thrp[0];

    const bool isL1 = lane < NL1;
    const bool isL2 = (lane >= NL1) && (lane < NL1 + NL2);

    // layer-1 per-lane weights (f32 -> f64, exact)
    double w1r[NIN];
    #pragma unroll
    for (int i = 0; i < NIN; ++i)
        w1r[i] = isL1 ? (double)W1[lane * NIN + i] : 0.0;
    double vj  = isL1 ? (double)V[lane] : 0.0;
    double vj0 = vj * 0.0;                 // signed zero matching V*0.0

    // layer-2 per-lane weight row (k=0 fallback keeps address in-bounds;
    // idle lanes compute garbage that is never stored or balloted into cur2)
    double w2r[NL1];
    {
        const int k = isL2 ? (lane - NL1) : 0;
        #pragma unroll
        for (int j = 0; j < NL1; ++j)
            w2r[j] = (double)W2[k * NL1 + j];
    }

    // ---- PIN weights in VGPRs: opaque asm def prevents the register
    // allocator from rematerializing the loads inside the time loop.
    #pragma unroll
    for (int i = 0; i < NIN; ++i) asm volatile("" : "+v"(w1r[i]));
    #pragma unroll
    for (int j = 0; j < NL1; ++j) asm volatile("" : "+v"(w2r[j]));
    asm volatile("" : "+v"(vj));
    asm volatile("" : "+v"(vj0));

    const double beta_l = isL1 ? beta1 : beta2;

    const int S1   = T_STEPS * BATCH * NL1;
    const int S2   = T_STEPS * BATCH * NL2;
    const int str1 = BATCH * NL1;
    const int str2 = BATCH * NL2;

    // per-lane store offsets; L2 lanes lag one step (skew): at iteration t the
    // L2 slot is (t-1), guarded by t>0. Idle lanes: stride 0, never store.
    int os, om, stride;
    if (isL1) {
        os = b * NL1 + lane;                 om = os + S1; stride = str1;
    } else if (isL2) {
        os = 2 * S1 + b * NL2 + (lane - NL1) - str2;
        om = os + S2;                        stride = str2;
    } else {
        os = 0; om = 0; stride = 0;
    }

    // Hoisted range check: the largest offset this lane ever stores is
    // bounded by om + T_STEPS*stride (om > os always). One check, loop-free.
    const bool safeAll = ((long long)om + (long long)T_STEPS * stride) < (long long)out_n;

    // x as float4: NIN=12 floats = 3 quads; 48B per element, 16B-aligned.
    const float4* xq   = reinterpret_cast<const float4*>(x) + (size_t)b * (NIN / 4);
    const int     QSTEP = BATCH * (NIN / 4);

    // 2-deep prefetch pipeline: a* = x(t), c* = x(t+1); loop loads x(t+2).
    float4 a0 = xq[0],         a1 = xq[1],         a2 = xq[2];
    float4 c0 = xq[QSTEP + 0], c1 = xq[QSTEP + 1], c2 = xq[QSTEP + 2];
    const float4* xn = xq + 2 * QSTEP;     // points at x(t+2)

    double mem = 0.0;
    bool sp_prev = false;
    unsigned long long mask_prev = 0ull;

    #pragma unroll 2
    for (int t = 0; t < T_STEPS; ++t) {
        // ---- prefetch x(t+2); tail re-reads an in-bounds earlier slice ----
        const float4* p = (t + 2 < T_STEPS) ? xn : (xn - 2 * QSTEP);
        const float4 n0 = p[0], n1 = p[1], n2 = p[2];
        xn += QSTEP;

        // ---- cur2 for step t-1: 4 interleaved partial chains ----
        // mask_prev is wave-uniform (SGPR): bsel is a scalar cselect feeding
        // v_fma_f64 (one SGPR-pair operand allowed); chains p0..p3 are
        // independent -> dependent-latency ~1/4 of a single 38-chain.
        double p0 = 0.0, p1 = 0.0, p2 = 0.0, p3 = 0.0;
        #pragma unroll
        for (int j = 0; j + 3 < NL1; j += 4) {
            const double s0 = ((mask_prev >> (j + 0)) & 1ull) ? 1.0 : 0.0;
            const double s1 = ((mask_prev >> (j + 1)) & 1ull) ? 1.0 : 0.0;
            const double s2 = ((mask_prev >> (j + 2)) & 1ull) ? 1.0 : 0.0;
            const double s3 = ((mask_prev >> (j + 3)) & 1ull) ? 1.0 : 0.0;
            p0 = __builtin_fma(s0, w2r[j + 0], p0);
            p1 = __builtin_fma(s1, w2r[j + 1], p1);
            p2 = __builtin_fma(s2, w2r[j + 2], p2);
            p3 = __builtin_fma(s3, w2r[j + 3], p3);
        }
        {   // tail: j = 36, 37
            const double s0 = ((mask_prev >> 36) & 1ull) ? 1.0 : 0.0;
            const double s1 = ((mask_prev >> 37) & 1ull) ? 1.0 : 0.0;
            p0 = __builtin_fma(s0, w2r[36], p0);
            p1 = __builtin_fma(s1, w2r[37], p1);
        }
        const double cur2 = (p0 + p1) + (p2 + p3);

        // ---- cur1 for step t from x(t): 2 interleaved partial chains ----
        const float xf[NIN] = { a0.x, a0.y, a0.z, a0.w,
                                a1.x, a1.y, a1.z, a1.w,
                                a2.x, a2.y, a2.z, a2.w };
        double q0 = 0.0, q1 = 0.0;
        #pragma unroll
        for (int i = 0; i < NIN; i += 2) {
            q0 = __builtin_fma((double)xf[i],     w1r[i],     q0);
            q1 = __builtin_fma((double)xf[i + 1], w1r[i + 1], q1);
        }
        const double cur1 = q0 + q1;

        // ---- unified membrane update (L1 @ t, L2 @ t-1) ----
        const double cur  = isL1 ? cur1 : cur2;
        const double vsel = sp_prev ? vj : vj0;     // +0.0 on L2/idle lanes
        mem = ((beta_l * mem) + cur) + vsel;
        const double d = mem - thr;
        const bool sp  = d > 0.0;
        mem = sp ? d : mem;
        sp_prev   = sp;
        mask_prev = __ballot(sp);      // bits >= NL1 never read by cur2

        const float sps  = sp ? 1.0f : 0.0f;
        const float memf = (float)mem;
        const bool actp  = (isL1 | (isL2 & (t > 0))) & safeAll;
        if (actp) {
            __builtin_nontemporal_store(sps,  &out[os]);
            __builtin_nontemporal_store(memf, &out[om]);
        }
        os += stride; om += stride;

        // rotate prefetch buffers (unroll-2 elides the copies)
        a0 = c0; a1 = c1; a2 = c2;
        c0 = n0; c1 = n1; c2 = n2;
    }

    // ---- epilogue: layer 2 for step T-1 (same partial-chain order) ----
    {
        double p0 = 0.0, p1 = 0.0, p2 = 0.0, p3 = 0.0;
        #pragma unroll
        for (int j = 0; j + 3 < NL1; j += 4) {
            const double s0 = ((mask_prev >> (j + 0)) & 1ull) ? 1.0 : 0.0;
            const double s1 = ((mask_prev >> (j + 1)) & 1ull) ? 1.0 : 0.0;
            const double s2 = ((mask_prev >> (j + 2)) & 1ull) ? 1.0 : 0.0;
            const double s3 = ((mask_prev >> (j + 3)) & 1ull) ? 1.0 : 0.0;
            p0 = __builtin_fma(s0, w2r[j + 0], p0);
            p1 = __builtin_fma(s1, w2r[j + 1], p1);
            p2 = __builtin_fma(s2, w2r[j + 2], p2);
            p3 = __builtin_fma(s3, w2r[j + 3], p3);
        }
        {
            const double s0 = ((mask_prev >> 36) & 1ull) ? 1.0 : 0.0;
            const double s1 = ((mask_prev >> 37) & 1ull) ? 1.0 : 0.0;
            p0 = __builtin_fma(s0, w2r[36], p0);
            p1 = __builtin_fma(s1, w2r[37], p1);
        }
        const double cur2 = (p0 + p1) + (p2 + p3);
        if (isL2 && safeAll) {
            double m2 = (beta2 * mem) + cur2;
            const double d2 = m2 - thr;
            const bool sp2 = d2 > 0.0;
            m2 = sp2 ? d2 : m2;
            __builtin_nontemporal_store(sp2 ? 1.0f : 0.0f, &out[os]);
            __builtin_nontemporal_store((float)m2,          &out[om]);
        }
    }
}

extern "C" void kernel_launch(void* const* d_in, const int* in_sizes, int n_in,
                              void* d_out, int out_size, void* d_ws, size_t ws_size,
                              hipStream_t stream) {
    // Default: dict order (x, W1, V, W2, beta1, beta2, threshold).
    const void* x   = d_in[0];
    const void* W1p = (n_in > 1) ? d_in[1] : d_in[0];
    const void* Vp  = (n_in > 2) ? d_in[2] : d_in[0];
    const void* W2p = (n_in > 3) ? d_in[3] : d_in[0];
    const void* b1  = (n_in > 4) ? d_in[4] : d_in[0];
    const void* b2  = (n_in > 5) ? d_in[5] : d_in[0];
    const void* th  = (n_in > 6) ? d_in[6] : d_in[0];

    // Size-based override (element counts), only replaces on exact match.
    {
        const void* sc[3] = {0, 0, 0};
        int ns = 0;
        for (int i = 0; i < n_in; ++i) {
            const int s = in_sizes[i];
            if      (s == T_STEPS * BATCH * NIN) x   = d_in[i];
            else if (s == NL1 * NIN)             W1p = d_in[i];
            else if (s == NL2 * NL1)             W2p = d_in[i];
            else if (s == NL1)                   Vp  = d_in[i];
            else if (s == 1 && ns < 3)           sc[ns++] = d_in[i];
        }
        if (ns == 3) { b1 = sc[0]; b2 = sc[1]; th = sc[2]; }
    }

    snn_kernel<<<BATCH / 4, 256, 0, stream>>>(
        (const float*)x, (const float*)W1p, (const float*)Vp, (const float*)W2p,
        (const float*)b1, (const float*)b2, (const float*)th,
        (float*)d_out, out_size);
}

// Round 12
// 866.513 us; speedup vs baseline: 1.0372x; 1.0372x over previous
//
#include <hip/hip_runtime.h>

#define T_STEPS 500
#define BATCH   2048
#define NIN     12
#define NL1     38
#define NL2     7

// fp32 I/O, FLOAT64 internal math (inputs promoted f32->f64 exactly; all ops
// f64; outputs cast f64->f32 on store). Numerics notes:
//   - cur1 = x . W1[row]: f64 FMAs, 2 interleaved partial chains + 1 add.
//   - cur2 = sum of selected W2 row entries (spikes in {0,1}): f64 FMAs with
//     scalar-selected multiplier in {0.0,1.0}, 4 partial chains + 3 adds.
//     Reassociation perturbation ~1e-15/step; harness passes at absmax
//     3.1e-2 (measured r6/r8/r9) — 13 orders of magnitude of headroom.
//   - V*spk1 as (sp ? vj : vj*0.0); mem - spk*thr as (sp ? mem-thr : mem) —
//     both exact vs the f64 ops they replace.
//
// Schedule:
//   - OCCUPANCY TARGET = 2 WAVES/EU (rounds 10-12, pending measurement):
//     amdgpu_waves_per_eu(2,2). History: r6/r8/r9 PMC all show VGPR_Count
//     64-68 — the allocator targets MAX occupancy regardless of
//     __launch_bounds__(256,2) (min-only) and regardless of asm pinning
//     (r9: +4 VGPRs, spilled/refilled anyway). 64 VGPRs cannot hold
//     w2r[38]=76 + w1r[12]=24 VGPRs of weights, so ~50 f64 refills run
//     INSIDE the time loop every step (invisible in FETCH_SIZE: L1 hits),
//     stalling the serial f64 chains: VALUBusy 31-40%, 349-600us.
//     Setting max waves/EU = 2 tells the allocator the truth (grid =
//     2048 waves / 1024 SIMDs = 2/SIMD, occupancy is grid-limited) so
//     register-saving buys nothing: budget 256, need ~180, no spills.
//     FALSIFIER: VGPR_Count must jump to >=150, else theory dead ->
//     next round goes to the 3-phase split (no phase needs >64 VGPRs).
//   - chain splits (cur2 4-way, cur1 2-way) retained: with a real register
//     budget they cut the per-step dependent-latency ~4x; under the old
//     64-VGPR budget they REGRESSED (r8/r9 600us vs r6 349us) by adding
//     live temps to an already-starved allocation.
//   - layer 2 skewed one step: iteration t computes L1(t) and L2(t-1);
//     epilogue finishes L2(T-1).
//   - UNIFIED membrane update folds L1/L2 updates + stores into one path.
//   - x prefetched 2 steps ahead as 3x float4.
//   - b pinned wave-uniform via readfirstlane (scalar x-address chain).
//   - bounds checks hoisted (audited: safeAll TRUE at exact output size).
//   - NONTEMPORAL output stores (write stream never re-read in-kernel).
// One wave per batch element: lanes 0..37 = layer-1 neurons, 38..44 = layer-2.
__global__ __launch_bounds__(256)
__attribute__((amdgpu_waves_per_eu(2, 2)))
void snn_kernel(
    const float* __restrict__ x,  const float* __restrict__ W1,
    const float* __restrict__ V,  const float* __restrict__ W2,
    const float* __restrict__ b1p, const float* __restrict__ b2p,
    const float* __restrict__ thrp, float* __restrict__ out, int out_n)
{
#pragma clang fp contract(off)
    const int tid  = threadIdx.x;
    const int lane = tid & 63;
    const int wave = tid >> 6;
    // b is wave-uniform by construction; readfirstlane makes that visible to
    // the compiler (SGPR), scalarizing the x-address chain below.
    const int b    = __builtin_amdgcn_readfirstlane(blockIdx.x * 4 + wave);

    const double beta1 = (double)b1p[0];
    const double beta2 = (double)b2p[0];
    const double thr   = (double)thrp[0];

    const bool isL1 = lane < NL1;
    const bool isL2 = (lane >= NL1) && (lane < NL1 + NL2);

    // layer-1 per-lane weights (f32 -> f64, exact)
    double w1r[NIN];
    #pragma unroll
    for (int i = 0; i < NIN; ++i)
        w1r[i] = isL1 ? (double)W1[lane * NIN + i] : 0.0;
    double vj  = isL1 ? (double)V[lane] : 0.0;
    double vj0 = vj * 0.0;                 // signed zero matching V*0.0

    // layer-2 per-lane weight row (k=0 fallback keeps address in-bounds;
    // idle lanes compute garbage that is never stored or balloted into cur2)
    double w2r[NL1];
    {
        const int k = isL2 ? (lane - NL1) : 0;
        #pragma unroll
        for (int j = 0; j < NL1; ++j)
            w2r[j] = (double)W2[k * NL1 + j];
    }

    // ---- PIN weights in VGPRs: opaque asm def discourages rematerializing
    // the loads inside the time loop (with the (2,2) budget it can stick).
    #pragma unroll
    for (int i = 0; i < NIN; ++i) asm volatile("" : "+v"(w1r[i]));
    #pragma unroll
    for (int j = 0; j < NL1; ++j) asm volatile("" : "+v"(w2r[j]));
    asm volatile("" : "+v"(vj));
    asm volatile("" : "+v"(vj0));

    const double beta_l = isL1 ? beta1 : beta2;

    const int S1   = T_STEPS * BATCH * NL1;
    const int S2   = T_STEPS * BATCH * NL2;
    const int str1 = BATCH * NL1;
    const int str2 = BATCH * NL2;

    // per-lane store offsets; L2 lanes lag one step (skew): at iteration t the
    // L2 slot is (t-1), guarded by t>0. Idle lanes: stride 0, never store.
    int os, om, stride;
    if (isL1) {
        os = b * NL1 + lane;                 om = os + S1; stride = str1;
    } else if (isL2) {
        os = 2 * S1 + b * NL2 + (lane - NL1) - str2;
        om = os + S2;                        stride = str2;
    } else {
        os = 0; om = 0; stride = 0;
    }

    // Hoisted range check: the largest offset this lane ever stores is
    // bounded by om + T_STEPS*stride (om > os always). One check, loop-free.
    const bool safeAll = ((long long)om + (long long)T_STEPS * stride) < (long long)out_n;

    // x as float4: NIN=12 floats = 3 quads; 48B per element, 16B-aligned.
    const float4* xq   = reinterpret_cast<const float4*>(x) + (size_t)b * (NIN / 4);
    const int     QSTEP = BATCH * (NIN / 4);

    // 2-deep prefetch pipeline: a* = x(t), c* = x(t+1); loop loads x(t+2).
    float4 a0 = xq[0],         a1 = xq[1],         a2 = xq[2];
    float4 c0 = xq[QSTEP + 0], c1 = xq[QSTEP + 1], c2 = xq[QSTEP + 2];
    const float4* xn = xq + 2 * QSTEP;     // points at x(t+2)

    double mem = 0.0;
    bool sp_prev = false;
    unsigned long long mask_prev = 0ull;

    #pragma unroll 2
    for (int t = 0; t < T_STEPS; ++t) {
        // ---- prefetch x(t+2); tail re-reads an in-bounds earlier slice ----
        const float4* p = (t + 2 < T_STEPS) ? xn : (xn - 2 * QSTEP);
        const float4 n0 = p[0], n1 = p[1], n2 = p[2];
        xn += QSTEP;

        // ---- cur2 for step t-1: 4 interleaved partial chains ----
        // mask_prev is wave-uniform (SGPR): bsel is a scalar cselect feeding
        // v_fma_f64 (one SGPR-pair operand allowed); chains p0..p3 are
        // independent -> dependent-latency ~1/4 of a single 38-chain.
        double p0 = 0.0, p1 = 0.0, p2 = 0.0, p3 = 0.0;
        #pragma unroll
        for (int j = 0; j + 3 < NL1; j += 4) {
            const double s0 = ((mask_prev >> (j + 0)) & 1ull) ? 1.0 : 0.0;
            const double s1 = ((mask_prev >> (j + 1)) & 1ull) ? 1.0 : 0.0;
            const double s2 = ((mask_prev >> (j + 2)) & 1ull) ? 1.0 : 0.0;
            const double s3 = ((mask_prev >> (j + 3)) & 1ull) ? 1.0 : 0.0;
            p0 = __builtin_fma(s0, w2r[j + 0], p0);
            p1 = __builtin_fma(s1, w2r[j + 1], p1);
            p2 = __builtin_fma(s2, w2r[j + 2], p2);
            p3 = __builtin_fma(s3, w2r[j + 3], p3);
        }
        {   // tail: j = 36, 37
            const double s0 = ((mask_prev >> 36) & 1ull) ? 1.0 : 0.0;
            const double s1 = ((mask_prev >> 37) & 1ull) ? 1.0 : 0.0;
            p0 = __builtin_fma(s0, w2r[36], p0);
            p1 = __builtin_fma(s1, w2r[37], p1);
        }
        const double cur2 = (p0 + p1) + (p2 + p3);

        // ---- cur1 for step t from x(t): 2 interleaved partial chains ----
        const float xf[NIN] = { a0.x, a0.y, a0.z, a0.w,
                                a1.x, a1.y, a1.z, a1.w,
                                a2.x, a2.y, a2.z, a2.w };
        double q0 = 0.0, q1 = 0.0;
        #pragma unroll
        for (int i = 0; i < NIN; i += 2) {
            q0 = __builtin_fma((double)xf[i],     w1r[i],     q0);
            q1 = __builtin_fma((double)xf[i + 1], w1r[i + 1], q1);
        }
        const double cur1 = q0 + q1;

        // ---- unified membrane update (L1 @ t, L2 @ t-1) ----
        const double cur  = isL1 ? cur1 : cur2;
        const double vsel = sp_prev ? vj : vj0;     // +0.0 on L2/idle lanes
        mem = ((beta_l * mem) + cur) + vsel;
        const double d = mem - thr;
        const bool sp  = d > 0.0;
        mem = sp ? d : mem;
        sp_prev   = sp;
        mask_prev = __ballot(sp);      // bits >= NL1 never read by cur2

        const float sps  = sp ? 1.0f : 0.0f;
        const float memf = (float)mem;
        const bool actp  = (isL1 | (isL2 & (t > 0))) & safeAll;
        if (actp) {
            __builtin_nontemporal_store(sps,  &out[os]);
            __builtin_nontemporal_store(memf, &out[om]);
        }
        os += stride; om += stride;

        // rotate prefetch buffers (unroll-2 elides the copies)
        a0 = c0; a1 = c1; a2 = c2;
        c0 = n0; c1 = n1; c2 = n2;
    }

    // ---- epilogue: layer 2 for step T-1 (same partial-chain order) ----
    {
        double p0 = 0.0, p1 = 0.0, p2 = 0.0, p3 = 0.0;
        #pragma unroll
        for (int j = 0; j + 3 < NL1; j += 4) {
            const double s0 = ((mask_prev >> (j + 0)) & 1ull) ? 1.0 : 0.0;
            const double s1 = ((mask_prev >> (j + 1)) & 1ull) ? 1.0 : 0.0;
            const double s2 = ((mask_prev >> (j + 2)) & 1ull) ? 1.0 : 0.0;
            const double s3 = ((mask_prev >> (j + 3)) & 1ull) ? 1.0 : 0.0;
            p0 = __builtin_fma(s0, w2r[j + 0], p0);
            p1 = __builtin_fma(s1, w2r[j + 1], p1);
            p2 = __builtin_fma(s2, w2r[j + 2], p2);
            p3 = __builtin_fma(s3, w2r[j + 3], p3);
        }
        {
            const double s0 = ((mask_prev >> 36) & 1ull) ? 1.0 : 0.0;
            const double s1 = ((mask_prev >> 37) & 1ull) ? 1.0 : 0.0;
            p0 = __builtin_fma(s0, w2r[36], p0);
            p1 = __builtin_fma(s1, w2r[37], p1);
        }
        const double cur2 = (p0 + p1) + (p2 + p3);
        if (isL2 && safeAll) {
            double m2 = (beta2 * mem) + cur2;
            const double d2 = m2 - thr;
            const bool sp2 = d2 > 0.0;
            m2 = sp2 ? d2 : m2;
            __builtin_nontemporal_store(sp2 ? 1.0f : 0.0f, &out[os]);
            __builtin_nontemporal_store((float)m2,          &out[om]);
        }
    }
}

extern "C" void kernel_launch(void* const* d_in, const int* in_sizes, int n_in,
                              void* d_out, int out_size, void* d_ws, size_t ws_size,
                              hipStream_t stream) {
    // Default: dict order (x, W1, V, W2, beta1, beta2, threshold).
    const void* x   = d_in[0];
    const void* W1p = (n_in > 1) ? d_in[1] : d_in[0];
    const void* Vp  = (n_in > 2) ? d_in[2] : d_in[0];
    const void* W2p = (n_in > 3) ? d_in[3] : d_in[0];
    const void* b1  = (n_in > 4) ? d_in[4] : d_in[0];
    const void* b2  = (n_in > 5) ? d_in[5] : d_in[0];
    const void* th  = (n_in > 6) ? d_in[6] : d_in[0];

    // Size-based override (element counts), only replaces on exact match.
    {
        const void* sc[3] = {0, 0, 0};
        int ns = 0;
        for (int i = 0; i < n_in; ++i) {
            const int s = in_sizes[i];
            if      (s == T_STEPS * BATCH * NIN) x   = d_in[i];
            else if (s == NL1 * NIN)             W1p = d_in[i];
            else if (s == NL2 * NL1)             W2p = d_in[i];
            else if (s == NL1)                   Vp  = d_in[i];
            else if (s == 1 && ns < 3)           sc[ns++] = d_in[i];
        }
        if (ns == 3) { b1 = sc[0]; b2 = sc[1]; th = sc[2]; }
    }

    snn_kernel<<<BATCH / 4, 256, 0, stream>>>(
        (const float*)x, (const float*)W1p, (const float*)Vp, (const float*)W2p,
        (const float*)b1, (const float*)b2, (const float*)th,
        (float*)d_out, out_size);
}

// Round 16
// 652.077 us; speedup vs baseline: 1.3782x; 1.3289x over previous
//
#include <hip/hip_runtime.h>

#define T_STEPS 500
#define BATCH   2048
#define NIN     12
#define NL1     38
#define NL2     7

// fp32 I/O, FLOAT64 internal math (inputs promoted f32->f64 exactly; all ops
// f64; outputs cast f64->f32 on store). Numerics:
//   - cur1 = x . W1[row]: sequential f64 FMA ascending k (r6-verified order).
//     Weights stored f32, promoted at use: (double)w1f[i] is EXACT, so the
//     f64 op sequence is bit-identical to holding f64 weights.
//   - cur2: spikes {0,1} -> sequential ascending-j fma(bsel,(double)w2f[j],.)
//     bsel in {0.0,1.0} (scalar cselect from wave-uniform ballot mask).
//   - V*spk1 as (sp ? vj : vj*0.0); mem - spk*thr as (sp ? mem-thr : mem).
//   All bit-identical to the r6-measured kernel (349us dispatch, passed).
//
// Schedule (evidence-driven, rounds 6-12):
//   - F32 WEIGHT STORAGE: r6/r8/r9/r12 PMC show the allocator caps
//     VGPRs at 64/68/68/88 and REMATERIALIZES f64 weight loads inside the
//     time loop (L1 refills, invisible in FETCH_SIZE) — w2r[38] f64 = 76
//     VGPRs never fit. Storing f32 halves the resident footprint to 50
//     VGPRs (fits ~88), and even if the compiler hoists the f64 promotion
//     and later remats it, the remat is a 2-4cy v_cvt_f64_f32 from a
//     resident f32 — VALU-only, no load latency. Root-cause fix either way.
//   - SERIAL chains restored (r6 form): machine-independent busy-time
//     (VALUBusy x dur) = 140us-equiv for r6 serial vs 181-186 for the
//     r8/r9/r12 4-way split — the split added ~30% issue (temps + remat
//     pressure). Reverted.
//   - waves_per_eu(2,2) kept: grid = 2048 waves / 1024 SIMDs = 2/SIMD,
//     so max=2 concedes nothing; r12 showed it lifts the cap (88) a bit.
//   - layer 2 skewed one step (L2 @ t-1), epilogue finishes L2(T-1).
//   - UNIFIED membrane update (one op path for L1/L2 lanes).
//   - x prefetched 2 steps ahead as 3x float4; b via readfirstlane.
//   - bounds hoisted (safeAll TRUE at exact out size; audited r5).
//   - NONTEMPORAL stores (write stream never re-read in-kernel).
// One wave per batch element: lanes 0..37 = layer-1 neurons, 38..44 = layer-2.
__global__ __launch_bounds__(256)
__attribute__((amdgpu_waves_per_eu(2, 2)))
void snn_kernel(
    const float* __restrict__ x,  const float* __restrict__ W1,
    const float* __restrict__ V,  const float* __restrict__ W2,
    const float* __restrict__ b1p, const float* __restrict__ b2p,
    const float* __restrict__ thrp, float* __restrict__ out, int out_n)
{
#pragma clang fp contract(off)
    const int tid  = threadIdx.x;
    const int lane = tid & 63;
    const int wave = tid >> 6;
    // b is wave-uniform by construction; readfirstlane makes that visible.
    const int b    = __builtin_amdgcn_readfirstlane(blockIdx.x * 4 + wave);

    const double beta1 = (double)b1p[0];
    const double beta2 = (double)b2p[0];
    const double thr   = (double)thrp[0];

    const bool isL1 = lane < NL1;
    const bool isL2 = (lane >= NL1) && (lane < NL1 + NL2);

    // layer-1 per-lane weights, stored f32 (12 VGPRs; promotion at use is exact)
    float w1f[NIN];
    #pragma unroll
    for (int i = 0; i < NIN; ++i)
        w1f[i] = isL1 ? W1[lane * NIN + i] : 0.0f;
    double vj  = isL1 ? (double)V[lane] : 0.0;
    double vj0 = vj * 0.0;                 // signed zero matching V*0.0

    // layer-2 per-lane weight row, stored f32 (38 VGPRs; k=0 fallback keeps
    // addresses in-bounds; idle lanes' results never stored/balloted into cur2)
    float w2f[NL1];
    {
        const int k = isL2 ? (lane - NL1) : 0;
        #pragma unroll
        for (int j = 0; j < NL1; ++j)
            w2f[j] = W2[k * NL1 + j];
    }

    // Pin the f32 weights: opaque asm defs make them un-rematerializable as
    // LOADS (any spill heuristic now remats at worst the cheap cvt).
    #pragma unroll
    for (int i = 0; i < NIN; ++i) asm volatile("" : "+v"(w1f[i]));
    #pragma unroll
    for (int j = 0; j < NL1; ++j) asm volatile("" : "+v"(w2f[j]));
    asm volatile("" : "+v"(vj));
    asm volatile("" : "+v"(vj0));

    const double beta_l = isL1 ? beta1 : beta2;

    const int S1   = T_STEPS * BATCH * NL1;
    const int S2   = T_STEPS * BATCH * NL2;
    const int str1 = BATCH * NL1;
    const int str2 = BATCH * NL2;

    // per-lane store offsets; L2 lanes lag one step (skew), guarded by t>0.
    int os, om, stride;
    if (isL1) {
        os = b * NL1 + lane;                 om = os + S1; stride = str1;
    } else if (isL2) {
        os = 2 * S1 + b * NL2 + (lane - NL1) - str2;
        om = os + S2;                        stride = str2;
    } else {
        os = 0; om = 0; stride = 0;
    }

    // Hoisted range check (audited: TRUE at exact output size).
    const bool safeAll = ((long long)om + (long long)T_STEPS * stride) < (long long)out_n;

    // x as float4: NIN=12 floats = 3 quads; 48B per element, 16B-aligned.
    const float4* xq   = reinterpret_cast<const float4*>(x) + (size_t)b * (NIN / 4);
    const int     QSTEP = BATCH * (NIN / 4);

    // 2-deep prefetch pipeline: a* = x(t), c* = x(t+1); loop loads x(t+2).
    float4 a0 = xq[0],         a1 = xq[1],         a2 = xq[2];
    float4 c0 = xq[QSTEP + 0], c1 = xq[QSTEP + 1], c2 = xq[QSTEP + 2];
    const float4* xn = xq + 2 * QSTEP;     // points at x(t+2)

    double mem = 0.0;
    bool sp_prev = false;
    unsigned long long mask_prev = 0ull;

    #pragma unroll 2
    for (int t = 0; t < T_STEPS; ++t) {
        // ---- prefetch x(t+2); tail re-reads an in-bounds earlier slice ----
        const float4* p = (t + 2 < T_STEPS) ? xn : (xn - 2 * QSTEP);
        const float4 n0 = p[0], n1 = p[1], n2 = p[2];
        xn += QSTEP;

        // ---- cur2 for step t-1: sequential selected f64 FMAs (r6 order) ----
        // mask_prev is wave-uniform (SGPR): bsel is a scalar cselect; the
        // f32->f64 promotion of w2f[j] is exact (cheap VALU cvt, no load).
        double cur2 = 0.0;
        #pragma unroll
        for (int j = 0; j < NL1; ++j) {
            const double bsel = ((mask_prev >> j) & 1ull) ? 1.0 : 0.0;
            cur2 = __builtin_fma(bsel, (double)w2f[j], cur2);
        }

        // ---- cur1 for step t from x(t): sequential f64 FMAs (r6 order) ----
        const float xf[NIN] = { a0.x, a0.y, a0.z, a0.w,
                                a1.x, a1.y, a1.z, a1.w,
                                a2.x, a2.y, a2.z, a2.w };
        double cur1 = 0.0;
        #pragma unroll
        for (int i = 0; i < NIN; ++i)
            cur1 = __builtin_fma((double)xf[i], (double)w1f[i], cur1);

        // ---- unified membrane update (L1 @ t, L2 @ t-1) ----
        const double cur  = isL1 ? cur1 : cur2;
        const double vsel = sp_prev ? vj : vj0;     // +0.0 on L2/idle lanes
        mem = ((beta_l * mem) + cur) + vsel;
        const double d = mem - thr;
        const bool sp  = d > 0.0;
        mem = sp ? d : mem;
        sp_prev   = sp;
        mask_prev = __ballot(sp);      // bits >= NL1 never read by cur2

        const float sps  = sp ? 1.0f : 0.0f;
        const float memf = (float)mem;
        const bool actp  = (isL1 | (isL2 & (t > 0))) & safeAll;
        if (actp) {
            __builtin_nontemporal_store(sps,  &out[os]);
            __builtin_nontemporal_store(memf, &out[om]);
        }
        os += stride; om += stride;

        // rotate prefetch buffers (unroll-2 elides the copies)
        a0 = c0; a1 = c1; a2 = c2;
        c0 = n0; c1 = n1; c2 = n2;
    }

    // ---- epilogue: layer 2 for step T-1 (same sequential order) ----
    {
        double cur2 = 0.0;
        #pragma unroll
        for (int j = 0; j < NL1; ++j) {
            const double bsel = ((mask_prev >> j) & 1ull) ? 1.0 : 0.0;
            cur2 = __builtin_fma(bsel, (double)w2f[j], cur2);
        }
        if (isL2 && safeAll) {
            double m2 = (beta2 * mem) + cur2;
            const double d2 = m2 - thr;
            const bool sp2 = d2 > 0.0;
            m2 = sp2 ? d2 : m2;
            __builtin_nontemporal_store(sp2 ? 1.0f : 0.0f, &out[os]);
            __builtin_nontemporal_store((float)m2,          &out[om]);
        }
    }
}

extern "C" void kernel_launch(void* const* d_in, const int* in_sizes, int n_in,
                              void* d_out, int out_size, void* d_ws, size_t ws_size,
                              hipStream_t stream) {
    // Default: dict order (x, W1, V, W2, beta1, beta2, threshold).
    const void* x   = d_in[0];
    const void* W1p = (n_in > 1) ? d_in[1] : d_in[0];
    const void* Vp  = (n_in > 2) ? d_in[2] : d_in[0];
    const void* W2p = (n_in > 3) ? d_in[3] : d_in[0];
    const void* b1  = (n_in > 4) ? d_in[4] : d_in[0];
    const void* b2  = (n_in > 5) ? d_in[5] : d_in[0];
    const void* th  = (n_in > 6) ? d_in[6] : d_in[0];

    // Size-based override (element counts), only replaces on exact match.
    {
        const void* sc[3] = {0, 0, 0};
        int ns = 0;
        for (int i = 0; i < n_in; ++i) {
            const int s = in_sizes[i];
            if      (s == T_STEPS * BATCH * NIN) x   = d_in[i];
            else if (s == NL1 * NIN)             W1p = d_in[i];
            else if (s == NL2 * NL1)             W2p = d_in[i];
            else if (s == NL1)                   Vp  = d_in[i];
            else if (s == 1 && ns < 3)           sc[ns++] = d_in[i];
        }
        if (ns == 3) { b1 = sc[0]; b2 = sc[1]; th = sc[2]; }
    }

    snn_kernel<<<BATCH / 4, 256, 0, stream>>>(
        (const float*)x, (const float*)W1p, (const float*)Vp, (const float*)W2p,
        (const float*)b1, (const float*)b2, (const float*)th,
        (float*)d_out, out_size);
}